// Round 2
// baseline (92.364 us; speedup 1.0000x reference)
//
#include <hip/hip_runtime.h>

// Morph2D soft rank-order filter:
//   patches(3x3, zero-pad SAME) * se -> sort ascending -> dot softmax(rank)
// x: [32,512,512,1] fp32 -> out same shape.
//
// R15 = R14 restructured for occupancy/latency (probe: World A vs World B).
// Tile = 4 rows x 2 cols per thread (was 4x4): float2 dense loads, 1M threads.
//  - HBM traffic IDENTICAL to R14 (same 1.5x row read-amp, same write bytes).
//  - Per-thread VGPR state ~halved (R[6][4]+c[6]x2); __launch_bounds__(256,6)
//    pins >=6 waves/SIMD (24 waves/CU) vs R14's ~4.
//  - Total VALU issue ~constant (ops/px unchanged, 2x threads, half ops each).
// Keeps R14's uniform-SE fast path (shared column sorts) + general fallback,
// wave-uniform y-border zeroing, exec-masked halo loads, XCD swizzle.

#define HH 512
#define WW 512

#define RFL(x) __int_as_float(__builtin_amdgcn_readfirstlane(__float_as_int(x)))
#define MIN3(a,b,c) fminf(fminf(a,b),c)
#define MAX3(a,b,c) fmaxf(fmaxf(a,b),c)
#define MED3(a,b,c) __builtin_amdgcn_fmed3f(a,b,c)
#define TSORT(a,b,c) { float t0_=MIN3(a,b,c), t1_=MED3(a,b,c), t2_=MAX3(a,b,c); a=t0_; b=t1_; c=t2_; }

__global__ __launch_bounds__(256, 6) void morph2d_kernel(
    const float* __restrict__ x, const float* __restrict__ se9,
    const float* __restrict__ rank, float* __restrict__ out)
{
    // XCD-aware swizzle: contiguous chunk of blocks per XCD (4096 % 8 == 0)
    int nper = gridDim.x >> 3;
    int lb   = (blockIdx.x & 7) * nper + (blockIdx.x >> 3);
    int g    = lb * 256 + threadIdx.x;       // 1,048,576 total, exact

    int gx = g & 255;             // x-group of 2 px
    int rg = (g >> 8) & 127;      // row-group of 4 rows (wave-uniform)
    int b  = g >> 15;             // batch
    int x2 = gx << 1;
    int y0 = rg << 2;
    int lane = threadIdx.x & 63;

    const float* img = x + (size_t)b * (HH * WW);

    // clamped row offsets (rows 1..4 always in-bounds)
    int rowoff[6];
    #pragma unroll
    for (int r = 0; r < 6; ++r) {
        int ry = y0 - 1 + r;
        rowoff[r] = min(max(ry, 0), HH - 1) * WW;
    }

    // ---- dense loads: 6 x float2, all lanes, coalesced (8 B/lane) ----
    float2 c[6];
    #pragma unroll
    for (int r = 0; r < 6; ++r)
        c[r] = *(const float2*)(img + rowoff[r] + x2);

    // ---- halo loads: EXEC-MASKED — only lanes 0 / 63 issue traffic ----
    bool eL = (lane == 0)  && (x2 > 0);
    bool eR = (lane == 63) && (x2 + 2 < WW);
    float eg[6] = {0.f, 0.f, 0.f, 0.f, 0.f, 0.f};   // zero-pad default
    if (eL || eR) {
        int eoff = eL ? (x2 - 1) : (x2 + 2);
        #pragma unroll
        for (int r = 0; r < 6; ++r)
            eg[r] = img[rowoff[r] + eoff];
    }

    // ---- softmax(rank) (1/s folded) + se, scalarized, under load shadow ----
    float w0,w1,w2,w3,w4,w5,w6,w7,w8;
    float s0,s1,s2,s3,s4,s5,s6,s7,s8;
    {
        float e[9]; float s = 0.f;
        #pragma unroll
        for (int i = 0; i < 9; ++i) { e[i] = __expf(rank[i]); s += e[i]; }
        float inv = 1.0f / s;
        w0=RFL(e[0]*inv); w1=RFL(e[1]*inv); w2=RFL(e[2]*inv);
        w3=RFL(e[3]*inv); w4=RFL(e[4]*inv); w5=RFL(e[5]*inv);
        w6=RFL(e[6]*inv); w7=RFL(e[7]*inv); w8=RFL(e[8]*inv);
        s0=RFL(se9[0]); s1=RFL(se9[1]); s2=RFL(se9[2]); s3=RFL(se9[3]);
        s4=RFL(se9[4]); s5=RFL(se9[5]); s6=RFL(se9[6]); s7=RFL(se9[7]); s8=RFL(se9[8]);
    }

    // ---- reconstruct 4-col rows: halos from neighbor lanes ----
    float R[6][4];
    #pragma unroll
    for (int r = 0; r < 6; ++r) {
        float lw = __shfl_up(c[r].y, 1);     // lane i-1's c.y  (col x2-1)
        float rx = __shfl_down(c[r].x, 1);   // lane i+1's c.x  (col x2+2)
        float lf = (lane == 0)  ? eg[r] : lw;   // x2==0 -> eg==0 (zero-pad)
        float rt = (lane == 63) ? eg[r] : rx;   // x2+2==WW -> eg==0
        R[r][0] = lf; R[r][1] = c[r].x; R[r][2] = c[r].y; R[r][3] = rt;
    }

    // ---- y-border zeroing: wave-uniform, only rows 0/5 can be OOB ----
    if (y0 == 0) {
        #pragma unroll
        for (int cc = 0; cc < 4; ++cc) R[0][cc] = 0.f;
    }
    if (y0 == HH - 4) {
        #pragma unroll
        for (int cc = 0; cc < 4; ++cc) R[5][cc] = 0.f;
    }

    // ---- runtime-uniform SE detection (all wave-uniform scalars) ----
    bool uni = (s0==s1) && (s1==s2) && (s2==s3) && (s3==s4) &&
               (s4==s5) && (s5==s6) && (s6==s7) && (s7==s8) && (s0 > 0.f);

    if (uni) {
        // ===== FAST PATH: uniform se=a>0. sort(a*p)=a*sort(p); fold a into w.
        float W0=RFL(w0*s0), W1=RFL(w1*s0), W2=RFL(w2*s0);
        float W3=RFL(w3*s0), W4=RFL(w4*s0), W5=RFL(w5*s0);
        float W6=RFL(w6*s0), W7=RFL(w7*s0), W8=RFL(w8*s0);

        #pragma unroll
        for (int r = 0; r < 4; ++r) {
            // shared column sorts: 4 vertical triples serve 2 pixels
            float cs0[4], cs1[4], cs2[4];
            #pragma unroll
            for (int cc = 0; cc < 4; ++cc) {
                float u0 = R[r][cc], u1 = R[r+1][cc], u2 = R[r+2][cc];
                TSORT(u0, u1, u2)
                cs0[cc] = u0; cs1[cc] = u1; cs2[cc] = u2;
            }
            float res[2];
            #pragma unroll
            for (int j = 0; j < 2; ++j) {
                // tableau: columns (v0,v3,v6),(v1,v4,v7),(v2,v5,v8) pre-sorted
                float v0 = cs0[j], v1 = cs0[j+1], v2 = cs0[j+2];
                float v3 = cs1[j], v4 = cs1[j+1], v5 = cs1[j+2];
                float v6 = cs2[j], v7 = cs2[j+1], v8 = cs2[j+2];

                TSORT(v0, v1, v2)            // rows (cols stay sorted)
                TSORT(v3, v4, v5)
                TSORT(v6, v7, v8)
                float r1 = fminf(v1, v3), p = fmaxf(v1, v3);
                float r7 = fmaxf(v5, v7), q = fminf(v5, v7);
                TSORT(v2, v4, v6)            // anti-diagonal; v4 = rank 4
                float r2 = fminf(p, v2), r3 = fmaxf(p, v2);
                float r5 = fminf(q, v6), r6 = fmaxf(q, v6);

                float acc = v0 * W0;
                acc = fmaf(r1, W1, acc);
                acc = fmaf(r2, W2, acc);
                acc = fmaf(r3, W3, acc);
                acc = fmaf(v4, W4, acc);
                acc = fmaf(r5, W5, acc);
                acc = fmaf(r6, W6, acc);
                acc = fmaf(r7, W7, acc);
                acc = fmaf(v8, W8, acc);
                res[j] = acc;
            }
            float2 o = { res[0], res[1] };
            *(float2*)(out + (((size_t)b * HH + (y0 + r)) * WW + x2)) = o;
        }
    } else {
        // ===== GENERAL PATH: per-pixel se-weight + full 29-op sort =====
        #pragma unroll
        for (int r = 0; r < 4; ++r) {
            float res[2];
            #pragma unroll
            for (int j = 0; j < 2; ++j) {
                float v0 = R[r  ][j]*s0, v1 = R[r  ][j+1]*s1, v2 = R[r  ][j+2]*s2;
                float v3 = R[r+1][j]*s3, v4 = R[r+1][j+1]*s4, v5 = R[r+1][j+2]*s5;
                float v6 = R[r+2][j]*s6, v7 = R[r+2][j+1]*s7, v8 = R[r+2][j+2]*s8;

                TSORT(v0, v1, v2)            // rows
                TSORT(v3, v4, v5)
                TSORT(v6, v7, v8)
                TSORT(v0, v3, v6)            // cols (rows remain sorted)
                TSORT(v1, v4, v7)
                TSORT(v2, v5, v8)
                float r1 = fminf(v1, v3), p = fmaxf(v1, v3);
                float r7 = fmaxf(v5, v7), q = fminf(v5, v7);
                TSORT(v2, v4, v6)            // anti-diagonal; v4 = rank 4
                float r2 = fminf(p, v2), r3 = fmaxf(p, v2);
                float r5 = fminf(q, v6), r6 = fmaxf(q, v6);

                float acc = v0 * w0;
                acc = fmaf(r1, w1, acc);
                acc = fmaf(r2, w2, acc);
                acc = fmaf(r3, w3, acc);
                acc = fmaf(v4, w4, acc);
                acc = fmaf(r5, w5, acc);
                acc = fmaf(r6, w6, acc);
                acc = fmaf(r7, w7, acc);
                acc = fmaf(v8, w8, acc);
                res[j] = acc;
            }
            float2 o = { res[0], res[1] };
            *(float2*)(out + (((size_t)b * HH + (y0 + r)) * WW + x2)) = o;
        }
    }
}

extern "C" void kernel_launch(void* const* d_in, const int* in_sizes, int n_in,
                              void* d_out, int out_size, void* d_ws, size_t ws_size,
                              hipStream_t stream) {
    const float* x    = (const float*)d_in[0];
    const float* se   = (const float*)d_in[1];
    const float* rank = (const float*)d_in[2];
    float* out = (float*)d_out;

    const int total_threads = 32 * (HH / 4) * (WW / 2);   // 1,048,576
    morph2d_kernel<<<total_threads / 256, 256, 0, stream>>>(x, se, rank, out);
}

// Round 3
// 88.424 us; speedup vs baseline: 1.0446x; 1.0446x over previous
//
#include <hip/hip_runtime.h>

// Morph2D soft rank-order filter:
//   patches(3x3, zero-pad SAME) * se -> sort ascending -> dot softmax(rank)
// x: [32,512,512,1] fp32 -> out same shape.
//
// R16 = revert to R14, the best-measured variant (89.2 us).
// Session evidence: R13 (4x4, heavy ops) 90.2 / R14 (4x4, -30% ops) 89.2 /
// R15 (4x2, 2x occupancy) 92.4 -> kernel is insensitive to op count AND
// occupancy => bound by compulsory HBM traffic (~67 MB @ 6.3 TB/s ~ 11 us)
// inside a harness envelope (~43 us ws-poison + out-poison + reset dispatches).
// 4x4 float4 tile keeps 16 B/lane loads (coalescing sweet spot).
//
//  (a) y-mask: only rows 0/5 can be out-of-bounds; zero them under a
//      wave-uniform branch instead of 36 unconditional mask-muls.
//  (b) uniform-SE fast path (runtime-detected, wave-uniform): when all 9 SE
//      values equal a>0, sort(a*p)=a*sort(p), so `a` folds into the softmax
//      weights; horizontally adjacent pixels share their vertical 3-sorts
//      (6 column TSORTs per output row serve 4 pixels). Rank extraction is
//      valid for any doubly-sorted tableau (transpose-symmetric lemma).
//      General SE falls back to the per-pixel path (full correctness).

#define HH 512
#define WW 512

#define RFL(x) __int_as_float(__builtin_amdgcn_readfirstlane(__float_as_int(x)))
#define MIN3(a,b,c) fminf(fminf(a,b),c)
#define MAX3(a,b,c) fmaxf(fmaxf(a,b),c)
#define MED3(a,b,c) __builtin_amdgcn_fmed3f(a,b,c)
#define TSORT(a,b,c) { float t0_=MIN3(a,b,c), t1_=MED3(a,b,c), t2_=MAX3(a,b,c); a=t0_; b=t1_; c=t2_; }

__global__ __launch_bounds__(256) void morph2d_kernel(
    const float* __restrict__ x, const float* __restrict__ se9,
    const float* __restrict__ rank, float* __restrict__ out)
{
    // XCD-aware swizzle: contiguous chunk of blocks per XCD
    int nper = gridDim.x >> 3;
    int lb   = (blockIdx.x & 7) * nper + (blockIdx.x >> 3);
    int g    = lb * 256 + threadIdx.x;       // 524,288 total, exact

    int gx = g & 127;             // x-group of 4 px
    int rg = (g >> 7) & 127;      // row-group of 4 rows (wave-uniform)
    int b  = g >> 14;             // batch
    int x4 = gx << 2;
    int y0 = rg << 2;
    int lane = threadIdx.x & 63;

    const float* img = x + (size_t)b * (HH * WW);

    // clamped row offsets (rows 1..4 are always in-bounds)
    int rowoff[6];
    #pragma unroll
    for (int r = 0; r < 6; ++r) {
        int ry = y0 - 1 + r;
        rowoff[r] = min(max(ry, 0), HH - 1) * WW;
    }

    // ---- dense loads: 6 x float4, all lanes, perfectly coalesced ----
    float4 c[6];
    #pragma unroll
    for (int r = 0; r < 6; ++r)
        c[r] = *(const float4*)(img + rowoff[r] + x4);

    // ---- halo loads: EXEC-MASKED — only lanes 0 / 63 issue traffic ----
    bool eL = (lane == 0)  && (x4 > 0);
    bool eR = (lane == 63) && (x4 + 4 < WW);
    float eg[6] = {0.f, 0.f, 0.f, 0.f, 0.f, 0.f};   // zero-pad default
    if (eL || eR) {
        int eoff = eL ? (x4 - 1) : (x4 + 4);
        #pragma unroll
        for (int r = 0; r < 6; ++r)
            eg[r] = img[rowoff[r] + eoff];
    }

    // ---- softmax(rank) (1/s folded) + se, scalarized, under load shadow ----
    float w0,w1,w2,w3,w4,w5,w6,w7,w8;
    float s0,s1,s2,s3,s4,s5,s6,s7,s8;
    {
        float e[9]; float s = 0.f;
        #pragma unroll
        for (int i = 0; i < 9; ++i) { e[i] = __expf(rank[i]); s += e[i]; }
        float inv = 1.0f / s;
        w0=RFL(e[0]*inv); w1=RFL(e[1]*inv); w2=RFL(e[2]*inv);
        w3=RFL(e[3]*inv); w4=RFL(e[4]*inv); w5=RFL(e[5]*inv);
        w6=RFL(e[6]*inv); w7=RFL(e[7]*inv); w8=RFL(e[8]*inv);
        s0=RFL(se9[0]); s1=RFL(se9[1]); s2=RFL(se9[2]); s3=RFL(se9[3]);
        s4=RFL(se9[4]); s5=RFL(se9[5]); s6=RFL(se9[6]); s7=RFL(se9[7]); s8=RFL(se9[8]);
    }

    // ---- reconstruct 6-col rows: halos from neighbor lanes ----
    float R[6][6];
    #pragma unroll
    for (int r = 0; r < 6; ++r) {
        float lw = __shfl_up(c[r].w, 1);     // lane i-1's c.w  (col x4-1)
        float rx = __shfl_down(c[r].x, 1);   // lane i+1's c.x  (col x4+4)
        float lf = (lane == 0)  ? eg[r] : lw;   // x4==0 -> eg==0 (zero-pad)
        float rt = (lane == 63) ? eg[r] : rx;   // x4+4==WW -> eg==0
        R[r][0] = lf;     R[r][1] = c[r].x; R[r][2] = c[r].y;
        R[r][3] = c[r].z; R[r][4] = c[r].w; R[r][5] = rt;
    }

    // ---- y-border zeroing: wave-uniform, only rows 0/5 can be OOB ----
    if (y0 == 0) {
        #pragma unroll
        for (int cc = 0; cc < 6; ++cc) R[0][cc] = 0.f;
    }
    if (y0 == HH - 4) {
        #pragma unroll
        for (int cc = 0; cc < 6; ++cc) R[5][cc] = 0.f;
    }

    // ---- runtime-uniform SE detection (all wave-uniform scalars) ----
    bool uni = (s0==s1) && (s1==s2) && (s2==s3) && (s3==s4) &&
               (s4==s5) && (s5==s6) && (s6==s7) && (s7==s8) && (s0 > 0.f);

    if (uni) {
        // ===== FAST PATH: uniform se=a>0. sort(a*p)=a*sort(p); fold a into w.
        float W0=RFL(w0*s0), W1=RFL(w1*s0), W2=RFL(w2*s0);
        float W3=RFL(w3*s0), W4=RFL(w4*s0), W5=RFL(w5*s0);
        float W6=RFL(w6*s0), W7=RFL(w7*s0), W8=RFL(w8*s0);

        #pragma unroll
        for (int r = 0; r < 4; ++r) {
            // shared column sorts: 6 vertical triples serve 4 pixels
            float cs0[6], cs1[6], cs2[6];
            #pragma unroll
            for (int cc = 0; cc < 6; ++cc) {
                float u0 = R[r][cc], u1 = R[r+1][cc], u2 = R[r+2][cc];
                TSORT(u0, u1, u2)
                cs0[cc] = u0; cs1[cc] = u1; cs2[cc] = u2;
            }
            float res[4];
            #pragma unroll
            for (int j = 0; j < 4; ++j) {
                // tableau: columns (v0,v3,v6),(v1,v4,v7),(v2,v5,v8) pre-sorted
                float v0 = cs0[j], v1 = cs0[j+1], v2 = cs0[j+2];
                float v3 = cs1[j], v4 = cs1[j+1], v5 = cs1[j+2];
                float v6 = cs2[j], v7 = cs2[j+1], v8 = cs2[j+2];

                TSORT(v0, v1, v2)            // rows (cols stay sorted)
                TSORT(v3, v4, v5)
                TSORT(v6, v7, v8)
                float r1 = fminf(v1, v3), p = fmaxf(v1, v3);
                float r7 = fmaxf(v5, v7), q = fminf(v5, v7);
                TSORT(v2, v4, v6)            // anti-diagonal; v4 = rank 4
                float r2 = fminf(p, v2), r3 = fmaxf(p, v2);
                float r5 = fminf(q, v6), r6 = fmaxf(q, v6);

                float acc = v0 * W0;
                acc = fmaf(r1, W1, acc);
                acc = fmaf(r2, W2, acc);
                acc = fmaf(r3, W3, acc);
                acc = fmaf(v4, W4, acc);
                acc = fmaf(r5, W5, acc);
                acc = fmaf(r6, W6, acc);
                acc = fmaf(r7, W7, acc);
                acc = fmaf(v8, W8, acc);
                res[j] = acc;
            }
            float4 o = { res[0], res[1], res[2], res[3] };
            *(float4*)(out + (((size_t)b * HH + (y0 + r)) * WW + x4)) = o;
        }
    } else {
        // ===== GENERAL PATH: per-pixel se-weight + full 29-op sort =====
        #pragma unroll
        for (int r = 0; r < 4; ++r) {
            float res[4];
            #pragma unroll
            for (int j = 0; j < 4; ++j) {
                float v0 = R[r  ][j]*s0, v1 = R[r  ][j+1]*s1, v2 = R[r  ][j+2]*s2;
                float v3 = R[r+1][j]*s3, v4 = R[r+1][j+1]*s4, v5 = R[r+1][j+2]*s5;
                float v6 = R[r+2][j]*s6, v7 = R[r+2][j+1]*s7, v8 = R[r+2][j+2]*s8;

                TSORT(v0, v1, v2)            // rows
                TSORT(v3, v4, v5)
                TSORT(v6, v7, v8)
                TSORT(v0, v3, v6)            // cols (rows remain sorted)
                TSORT(v1, v4, v7)
                TSORT(v2, v5, v8)
                float r1 = fminf(v1, v3), p = fmaxf(v1, v3);
                float r7 = fmaxf(v5, v7), q = fminf(v5, v7);
                TSORT(v2, v4, v6)            // anti-diagonal; v4 = rank 4
                float r2 = fminf(p, v2), r3 = fmaxf(p, v2);
                float r5 = fminf(q, v6), r6 = fmaxf(q, v6);

                float acc = v0 * w0;
                acc = fmaf(r1, w1, acc);
                acc = fmaf(r2, w2, acc);
                acc = fmaf(r3, w3, acc);
                acc = fmaf(v4, w4, acc);
                acc = fmaf(r5, w5, acc);
                acc = fmaf(r6, w6, acc);
                acc = fmaf(r7, w7, acc);
                acc = fmaf(v8, w8, acc);
                res[j] = acc;
            }
            float4 o = { res[0], res[1], res[2], res[3] };
            *(float4*)(out + (((size_t)b * HH + (y0 + r)) * WW + x4)) = o;
        }
    }
}

extern "C" void kernel_launch(void* const* d_in, const int* in_sizes, int n_in,
                              void* d_out, int out_size, void* d_ws, size_t ws_size,
                              hipStream_t stream) {
    const float* x    = (const float*)d_in[0];
    const float* se   = (const float*)d_in[1];
    const float* rank = (const float*)d_in[2];
    float* out = (float*)d_out;

    const int total_threads = 32 * (HH / 4) * (WW / 4);   // 524,288
    morph2d_kernel<<<total_threads / 256, 256, 0, stream>>>(x, se, rank, out);
}